// Round 6
// baseline (740.527 us; speedup 1.0000x reference)
//
#include <hip/hip_runtime.h>

#define NN 50000
#define NE 800000
#define D  64
#define NL 2

typedef __bf16 bf16x8 __attribute__((ext_vector_type(8)));
typedef float  floatx4 __attribute__((ext_vector_type(4)));

static __device__ __forceinline__ float bf2f(unsigned short u) {
    return __uint_as_float(((unsigned)u) << 16);
}
static __device__ __forceinline__ unsigned short f2bf(float x) {
    unsigned u = __float_as_uint(x);
    u += 0x7fff + ((u >> 16) & 1);   // RNE
    return (unsigned short)(u >> 16);
}

// ---------------- CSR build (edge_index is identical for both layers) ----------------

__global__ void k_deg(const int* __restrict__ ei, int* __restrict__ deg) {
    int e = blockIdx.x * 256 + threadIdx.x;
    if (e < NE) atomicAdd(&deg[ei[NE + e]], 1);
}

// 2-phase scan: 1024 threads x 49-elem chunks, one 10-step block scan.
__global__ __launch_bounds__(1024) void k_scan(const int* __restrict__ deg,
        int* __restrict__ row_off, int* __restrict__ cursor) {
    __shared__ int sums[1024];
    const int t = threadIdx.x;
    const int CH = (NN + 1023) / 1024;           // 49
    int b = t * CH, e = b + CH; if (e > NN) e = NN; if (b > NN) b = NN;
    int s = 0;
    for (int i = b; i < e; i++) s += deg[i];
    sums[t] = s;
    __syncthreads();
    for (int off = 1; off < 1024; off <<= 1) {
        int v = (t >= off) ? sums[t - off] : 0;
        __syncthreads();
        sums[t] += v;
        __syncthreads();
    }
    int run = sums[t] - s;                        // exclusive prefix of chunk
    if (t == 0) row_off[0] = 0;
    for (int i = b; i < e; i++) {
        int d = deg[i];
        cursor[i] = run;
        run += d;
        row_off[i + 1] = run;
    }
}

// csr_src[pos] = src ; eperm[e] = pos
__global__ void k_scatter(const int* __restrict__ ei, int* __restrict__ cursor,
                          int* __restrict__ csr_src, int* __restrict__ eperm) {
    int e = blockIdx.x * 256 + threadIdx.x;
    if (e < NE) {
        int dst = ei[NE + e];
        int pos = atomicAdd(&cursor[dst], 1);
        csr_src[pos] = ei[e];
        eperm[e] = pos;
    }
}

// transpose all weights to bf16 m-major [m][k] once per call.
__global__ __launch_bounds__(256) void k_prep(
        const float* __restrict__ WQ, const float* __restrict__ WK,
        const float* __restrict__ WV, const float* __restrict__ WE,
        const float* __restrict__ WO, const float* __restrict__ W1,
        const float* __restrict__ W2,
        unsigned short* __restrict__ wqT, unsigned short* __restrict__ wkT,
        unsigned short* __restrict__ wvT, unsigned short* __restrict__ weT,
        unsigned short* __restrict__ woT, unsigned short* __restrict__ w1T,
        unsigned short* __restrict__ w2T) {
    int idx = blockIdx.x * 256 + threadIdx.x;
    if (idx >= 2 * 36864) return;
    int l = idx / 36864;
    int r = idx % 36864;
    if (r < 20480) {
        int which = r >> 12, rr = r & 4095;
        int m = rr >> 6, k = rr & 63;
        const float* src = (which == 0 ? WQ : which == 1 ? WK : which == 2 ? WV :
                            which == 3 ? WE : WO);
        unsigned short* dst = (which == 0 ? wqT : which == 1 ? wkT : which == 2 ? wvT :
                               which == 3 ? weT : woT);
        dst[l * 4096 + rr] = f2bf(src[l * 4096 + k * 64 + m]);
    } else if (r < 28672) {
        int r2 = r - 20480;
        int m = r2 >> 6, k = r2 & 63;
        w1T[l * 8192 + r2] = f2bf(W1[l * 8192 + k * 128 + m]);
    } else {
        int r3 = r - 28672;
        int m = r3 >> 7, k = r3 & 127;
        w2T[l * 8192 + r3] = f2bf(W2[l * 8192 + k * 64 + m]);
    }
}

// ---------------- kernels ----------------

// QKV via MFMA: one 16-node tile per wave. Q/K/V all bf16 via LDS staging.
__global__ __launch_bounds__(256) void k_qkv_mfma(const float* __restrict__ h,
        const unsigned short* __restrict__ wqT, const unsigned short* __restrict__ wkT,
        const unsigned short* __restrict__ wvT,
        unsigned short* __restrict__ Qb, unsigned short* __restrict__ Kb,
        unsigned short* __restrict__ Vb) {
    __shared__ unsigned short st[4][16 * 72];
    const int lane = threadIdx.x & 63;
    const int w    = threadIdx.x >> 6;
    const int ml   = lane & 15;
    const int quad = lane >> 4;

    bf16x8 aq[2][4], ak[2][4], av[2][4];
#pragma unroll
    for (int kt = 0; kt < 2; kt++)
#pragma unroll
        for (int mt = 0; mt < 4; mt++) {
            int o = (mt*16 + ml)*64 + kt*32 + quad*8;
            aq[kt][mt] = *(const bf16x8*)&wqT[o];
            ak[kt][mt] = *(const bf16x8*)&wkT[o];
            av[kt][mt] = *(const bf16x8*)&wvT[o];
        }

    const int wave = blockIdx.x * 4 + w;
    const int nw   = gridDim.x * 4;
    const int el = lane >> 2, c = lane & 3;
    for (int tile = wave; tile < NN / 16; tile += nw) {
        const int e0 = tile * 16;
        const float4* ar = (const float4*)(h + (size_t)(e0 + ml) * D);
        bf16x8 b[2];
#pragma unroll
        for (int kt = 0; kt < 2; kt++) {
            float4 f0 = ar[kt*8 + quad*2 + 0];
            float4 f1 = ar[kt*8 + quad*2 + 1];
            b[kt][0] = (__bf16)f0.x; b[kt][1] = (__bf16)f0.y;
            b[kt][2] = (__bf16)f0.z; b[kt][3] = (__bf16)f0.w;
            b[kt][4] = (__bf16)f1.x; b[kt][5] = (__bf16)f1.y;
            b[kt][6] = (__bf16)f1.z; b[kt][7] = (__bf16)f1.w;
        }
        floatx4 accq[4] = {}, acck[4] = {}, accv[4] = {};
#pragma unroll
        for (int kt = 0; kt < 2; kt++)
#pragma unroll
            for (int mt = 0; mt < 4; mt++) {
                accq[mt] = __builtin_amdgcn_mfma_f32_16x16x32_bf16(aq[kt][mt], b[kt], accq[mt], 0, 0, 0);
                acck[mt] = __builtin_amdgcn_mfma_f32_16x16x32_bf16(ak[kt][mt], b[kt], acck[mt], 0, 0, 0);
                accv[mt] = __builtin_amdgcn_mfma_f32_16x16x32_bf16(av[kt][mt], b[kt], accv[mt], 0, 0, 0);
            }
        unsigned short* outs[3] = {Qb, Kb, Vb};
        floatx4* accs[3] = {accq, acck, accv};
#pragma unroll
        for (int m = 0; m < 3; m++) {
            floatx4* a = accs[m];
#pragma unroll
            for (int mt = 0; mt < 4; mt++)
                *(ushort4*)&st[w][ml*72 + mt*16 + quad*4] =
                    make_ushort4(f2bf(a[mt][0]), f2bf(a[mt][1]),
                                 f2bf(a[mt][2]), f2bf(a[mt][3]));
            uint4 r0 = *(const uint4*)&st[w][el*72 + c*16 + 0];
            uint4 r1 = *(const uint4*)&st[w][el*72 + c*16 + 8];
            uint4* gp = (uint4*)(outs[m] + (size_t)(e0 + el) * D + c*16);
            gp[0] = r0; gp[1] = r1;
        }
    }
}

// Fused edge GEMM + score: stream edge_attr, Eh in regs (MFMA), gather bf16
// K[src]/Q[dst], reduce per head over quads, write exp(clip(s/4)) per (edge,head)
// in CSR order. head == mt because DH == 16.
__global__ __launch_bounds__(256) void k_score(const float* __restrict__ ea,
        const unsigned short* __restrict__ weT, const int* __restrict__ ei,
        const int* __restrict__ eperm,
        const unsigned short* __restrict__ Qb, const unsigned short* __restrict__ Kb,
        float* __restrict__ sc_out) {
    const int lane = threadIdx.x & 63;
    const int w    = threadIdx.x >> 6;
    const int ml   = lane & 15;
    const int quad = lane >> 4;

    bf16x8 afr[2][4];
#pragma unroll
    for (int kt = 0; kt < 2; kt++)
#pragma unroll
        for (int mt = 0; mt < 4; mt++)
            afr[kt][mt] = *(const bf16x8*)&weT[(mt*16 + ml)*64 + kt*32 + quad*8];

    const int wave = blockIdx.x * 4 + w;
    const int nw   = gridDim.x * 4;
    for (int tile = wave; tile < NE / 16; tile += nw) {
        const int e0 = tile * 16;
        const float4* ar = (const float4*)(ea + (size_t)(e0 + ml) * D);
        bf16x8 b[2];
#pragma unroll
        for (int kt = 0; kt < 2; kt++) {
            float4 f0 = ar[kt*8 + quad*2 + 0];
            float4 f1 = ar[kt*8 + quad*2 + 1];
            b[kt][0] = (__bf16)f0.x; b[kt][1] = (__bf16)f0.y;
            b[kt][2] = (__bf16)f0.z; b[kt][3] = (__bf16)f0.w;
            b[kt][4] = (__bf16)f1.x; b[kt][5] = (__bf16)f1.y;
            b[kt][6] = (__bf16)f1.z; b[kt][7] = (__bf16)f1.w;
        }
        int s_e = ei[e0 + ml];
        int d_e = ei[NE + e0 + ml];
        floatx4 acc[4] = {};
#pragma unroll
        for (int kt = 0; kt < 2; kt++)
#pragma unroll
            for (int mt = 0; mt < 4; mt++)
                acc[mt] = __builtin_amdgcn_mfma_f32_16x16x32_bf16(afr[kt][mt], b[kt], acc[mt], 0, 0, 0);
        // per-head score: dims mt*16 + quad*4 + r ; reduce over quads
        float sc4[4];
#pragma unroll
        for (int mt = 0; mt < 4; mt++) {
            ushort4 kk = *(const ushort4*)(Kb + (size_t)s_e * D + mt*16 + quad*4);
            ushort4 qq = *(const ushort4*)(Qb + (size_t)d_e * D + mt*16 + quad*4);
            float p = acc[mt][0] * bf2f(kk.x) * bf2f(qq.x)
                    + acc[mt][1] * bf2f(kk.y) * bf2f(qq.y)
                    + acc[mt][2] * bf2f(kk.z) * bf2f(qq.z)
                    + acc[mt][3] * bf2f(kk.w) * bf2f(qq.w);
            p += __shfl_xor(p, 16, 64);
            p += __shfl_xor(p, 32, 64);
            sc4[mt] = __expf(fminf(5.f, fmaxf(-5.f, p * 0.25f)));
        }
        if (quad == 0) {
            int pos = eperm[e0 + ml];
            *(float4*)(sc_out + (size_t)pos * 4) =
                make_float4(sc4[0], sc4[1], sc4[2], sc4[3]);
        }
    }
}

// aggregation: wave per node, 4 edge-slots x 16 dim-lanes, unroll x2.
// per edge: 1 broadcast score load + 1 V gather + 4 fma. No shuffles in loop.
__global__ __launch_bounds__(256) void k_agg(const unsigned short* __restrict__ Vb,
        const float* __restrict__ sc,
        const int* __restrict__ row_off, const int* __restrict__ csr_src,
        float* __restrict__ h_attn) {
    const int node = blockIdx.x * 4 + (threadIdx.x >> 6);
    if (node >= NN) return;
    const int lane  = threadIdx.x & 63;
    const int eslot = lane >> 4;
    const int ml    = lane & 15;
    const int head  = ml >> 2;
    const int beg = row_off[node], end = row_off[node + 1];
    float4 acc = make_float4(0.f, 0.f, 0.f, 0.f);
    float z = 0.f;

    for (int i0 = beg + eslot; i0 < end; i0 += 8) {
        int i1 = i0 + 4;
        bool a1 = i1 < end;
        int p1 = a1 ? i1 : i0;
        float s0 = sc[(size_t)i0 * 4 + head];
        float s1 = a1 ? sc[(size_t)p1 * 4 + head] : 0.f;
        int v0 = csr_src[i0];
        int v1 = csr_src[p1];
        ushort4 vb0 = *(const ushort4*)(Vb + (size_t)v0 * D + ml * 4);
        ushort4 vb1 = *(const ushort4*)(Vb + (size_t)v1 * D + ml * 4);
        acc.x += s0 * bf2f(vb0.x) + s1 * bf2f(vb1.x);
        acc.y += s0 * bf2f(vb0.y) + s1 * bf2f(vb1.y);
        acc.z += s0 * bf2f(vb0.z) + s1 * bf2f(vb1.z);
        acc.w += s0 * bf2f(vb0.w) + s1 * bf2f(vb1.w);
        z += s0 + s1;
    }
#pragma unroll
    for (int m = 16; m <= 32; m <<= 1) {
        acc.x += __shfl_xor(acc.x, m, 64);
        acc.y += __shfl_xor(acc.y, m, 64);
        acc.z += __shfl_xor(acc.z, m, 64);
        acc.w += __shfl_xor(acc.w, m, 64);
        z     += __shfl_xor(z, m, 64);
    }
    if (eslot == 0) {
        float inv = 1.f / (z + 1e-6f);
        ((float4*)(h_attn + (size_t)node * D))[ml] =
            make_float4(acc.x * inv, acc.y * inv, acc.z * inv, acc.w * inv);
    }
}

// MFMA-based fused post block: one 16-node tile per wave.
__global__ __launch_bounds__(512) void k_post_mfma(const float* __restrict__ h_in,
        const float* __restrict__ h_attn,
        const unsigned short* __restrict__ woT_g,
        const unsigned short* __restrict__ w1T_g,
        const unsigned short* __restrict__ w2T_g,
        const float* __restrict__ bo,
        const float* __restrict__ g1, const float* __restrict__ be1,
        const float* __restrict__ b1, const float* __restrict__ b2,
        const float* __restrict__ g2, const float* __restrict__ be2,
        float* __restrict__ h_out) {
    __shared__ unsigned short woT_s[64 * 72];
    __shared__ unsigned short w1T_s[128 * 72];
    __shared__ unsigned short w2T_s[64 * 136];
    __shared__ unsigned short stg[8][16 * 136];

    const int t = threadIdx.x;
    {
        const uint4* s0 = (const uint4*)woT_g;
        { int i = t; if (i < 512) { int row = i >> 3, c = i & 7;
              *(uint4*)&woT_s[row*72 + c*8] = s0[i]; } }
        const uint4* s1 = (const uint4*)w1T_g;
        for (int i = t; i < 1024; i += 512) {
            int row = i >> 3, c = i & 7;
            *(uint4*)&w1T_s[row*72 + c*8] = s1[i];
        }
        const uint4* s2 = (const uint4*)w2T_g;
        for (int i = t; i < 1024; i += 512) {
            int row = i >> 4, c = i & 15;
            *(uint4*)&w2T_s[row*136 + c*8] = s2[i];
        }
    }
    __syncthreads();

    const int w = t >> 6, lane = t & 63;
    const int ml = lane & 15, quad = lane >> 4;
    const int tile = blockIdx.x * 8 + w;
    if (tile >= NN / 16) return;
    const int e0 = tile * 16;
    unsigned short* st = stg[w];

    // ---- GEMM1: tt = h_attn @ WO
    const float4* ap = (const float4*)(h_attn + (size_t)(e0 + ml) * D);
    floatx4 acc1[4] = {};
#pragma unroll
    for (int kt = 0; kt < 2; kt++) {
        float4 f0 = ap[kt*8 + quad*2 + 0];
        float4 f1 = ap[kt*8 + quad*2 + 1];
        bf16x8 b;
        b[0] = (__bf16)f0.x; b[1] = (__bf16)f0.y; b[2] = (__bf16)f0.z; b[3] = (__bf16)f0.w;
        b[4] = (__bf16)f1.x; b[5] = (__bf16)f1.y; b[6] = (__bf16)f1.z; b[7] = (__bf16)f1.w;
#pragma unroll
        for (int mt = 0; mt < 4; mt++) {
            bf16x8 a = *(const bf16x8*)&woT_s[(mt*16 + ml)*72 + kt*32 + quad*8];
            acc1[mt] = __builtin_amdgcn_mfma_f32_16x16x32_bf16(a, b, acc1[mt], 0, 0, 0);
        }
    }
    const float4* hp  = (const float4*)(h_in + (size_t)(e0 + ml) * D);
    const float4* bo4 = (const float4*)bo;
    floatx4 tt[4];
#pragma unroll
    for (int mt = 0; mt < 4; mt++) {
        float4 hh = hp[mt*4 + quad];
        float4 bb = bo4[mt*4 + quad];
        tt[mt][0] = acc1[mt][0] + hh.x + bb.x;
        tt[mt][1] = acc1[mt][1] + hh.y + bb.y;
        tt[mt][2] = acc1[mt][2] + hh.z + bb.z;
        tt[mt][3] = acc1[mt][3] + hh.w + bb.w;
    }
    float s = 0.f;
#pragma unroll
    for (int mt = 0; mt < 4; mt++) s += tt[mt][0] + tt[mt][1] + tt[mt][2] + tt[mt][3];
    s += __shfl_xor(s, 16, 64); s += __shfl_xor(s, 32, 64);
    float mu = s * (1.f / 64.f);
    float v = 0.f;
#pragma unroll
    for (int mt = 0; mt < 4; mt++)
#pragma unroll
        for (int r = 0; r < 4; r++) { float c = tt[mt][r] - mu; v += c * c; }
    v += __shfl_xor(v, 16, 64); v += __shfl_xor(v, 32, 64);
    float rstd = rsqrtf(v * (1.f / 64.f) + 1e-5f);
    const float4* g1v  = (const float4*)g1;
    const float4* be1v = (const float4*)be1;
    floatx4 h1[4];
#pragma unroll
    for (int mt = 0; mt < 4; mt++) {
        float4 gg = g1v[mt*4 + quad];
        float4 bb = be1v[mt*4 + quad];
        h1[mt][0] = (tt[mt][0] - mu) * rstd * gg.x + bb.x;
        h1[mt][1] = (tt[mt][1] - mu) * rstd * gg.y + bb.y;
        h1[mt][2] = (tt[mt][2] - mu) * rstd * gg.z + bb.z;
        h1[mt][3] = (tt[mt][3] - mu) * rstd * gg.w + bb.w;
        *(ushort4*)&st[ml*136 + mt*16 + quad*4] =
            make_ushort4(f2bf(h1[mt][0]), f2bf(h1[mt][1]), f2bf(h1[mt][2]), f2bf(h1[mt][3]));
    }

    // ---- GEMM2: y = relu(h1 @ W1 + b1)
    bf16x8 bh[2];
#pragma unroll
    for (int kt = 0; kt < 2; kt++)
        bh[kt] = *(const bf16x8*)&st[ml*136 + kt*32 + quad*8];
    floatx4 acc2[8] = {};
#pragma unroll
    for (int kt = 0; kt < 2; kt++)
#pragma unroll
        for (int mt = 0; mt < 8; mt++) {
            bf16x8 a = *(const bf16x8*)&w1T_s[(mt*16 + ml)*72 + kt*32 + quad*8];
            acc2[mt] = __builtin_amdgcn_mfma_f32_16x16x32_bf16(a, bh[kt], acc2[mt], 0, 0, 0);
        }
    const float4* b1v = (const float4*)b1;
#pragma unroll
    for (int mt = 0; mt < 8; mt++) {
        float4 bb = b1v[mt*4 + quad];
        float y0 = fmaxf(acc2[mt][0] + bb.x, 0.f);
        float y1 = fmaxf(acc2[mt][1] + bb.y, 0.f);
        float y2 = fmaxf(acc2[mt][2] + bb.z, 0.f);
        float y3 = fmaxf(acc2[mt][3] + bb.w, 0.f);
        *(ushort4*)&st[ml*136 + mt*16 + quad*4] =
            make_ushort4(f2bf(y0), f2bf(y1), f2bf(y2), f2bf(y3));
    }

    // ---- GEMM3: z = y @ W2
    floatx4 acc3[4] = {};
#pragma unroll
    for (int kt = 0; kt < 4; kt++) {
        bf16x8 b = *(const bf16x8*)&st[ml*136 + kt*32 + quad*8];
#pragma unroll
        for (int mt = 0; mt < 4; mt++) {
            bf16x8 a = *(const bf16x8*)&w2T_s[(mt*16 + ml)*136 + kt*32 + quad*8];
            acc3[mt] = __builtin_amdgcn_mfma_f32_16x16x32_bf16(a, b, acc3[mt], 0, 0, 0);
        }
    }
    const float4* b2v = (const float4*)b2;
#pragma unroll
    for (int mt = 0; mt < 4; mt++) {
        float4 bb = b2v[mt*4 + quad];
        tt[mt][0] = acc3[mt][0] + bb.x + h1[mt][0];
        tt[mt][1] = acc3[mt][1] + bb.y + h1[mt][1];
        tt[mt][2] = acc3[mt][2] + bb.z + h1[mt][2];
        tt[mt][3] = acc3[mt][3] + bb.w + h1[mt][3];
    }
    s = 0.f;
#pragma unroll
    for (int mt = 0; mt < 4; mt++) s += tt[mt][0] + tt[mt][1] + tt[mt][2] + tt[mt][3];
    s += __shfl_xor(s, 16, 64); s += __shfl_xor(s, 32, 64);
    mu = s * (1.f / 64.f);
    v = 0.f;
#pragma unroll
    for (int mt = 0; mt < 4; mt++)
#pragma unroll
        for (int r = 0; r < 4; r++) { float c = tt[mt][r] - mu; v += c * c; }
    v += __shfl_xor(v, 16, 64); v += __shfl_xor(v, 32, 64);
    rstd = rsqrtf(v * (1.f / 64.f) + 1e-5f);
    const float4* g2v  = (const float4*)g2;
    const float4* be2v = (const float4*)be2;
    float4* outp = (float4*)(h_out + (size_t)(e0 + ml) * D);
#pragma unroll
    for (int mt = 0; mt < 4; mt++) {
        float4 gg = g2v[mt*4 + quad];
        float4 bb = be2v[mt*4 + quad];
        float4 o;
        o.x = (tt[mt][0] - mu) * rstd * gg.x + bb.x;
        o.y = (tt[mt][1] - mu) * rstd * gg.y + bb.y;
        o.z = (tt[mt][2] - mu) * rstd * gg.z + bb.z;
        o.w = (tt[mt][3] - mu) * rstd * gg.w + bb.w;
        outp[mt*4 + quad] = o;
    }
}

// ---------------- launch ----------------

extern "C" void kernel_launch(void* const* d_in, const int* in_sizes, int n_in,
                              void* d_out, int out_size, void* d_ws, size_t ws_size,
                              hipStream_t stream) {
    const float* x   = (const float*)d_in[0];
    const float* ea  = (const float*)d_in[1];
    const int*   ei  = (const int*)d_in[2];
    const float* WQ  = (const float*)d_in[3];
    const float* WK  = (const float*)d_in[4];
    const float* WE  = (const float*)d_in[5];
    const float* WV  = (const float*)d_in[6];
    const float* WO  = (const float*)d_in[7];
    const float* bO  = (const float*)d_in[8];
    const float* g1  = (const float*)d_in[9];
    const float* be1 = (const float*)d_in[10];
    const float* W1  = (const float*)d_in[11];
    const float* b1  = (const float*)d_in[12];
    const float* W2  = (const float*)d_in[13];
    const float* b2  = (const float*)d_in[14];
    const float* g2  = (const float*)d_in[15];
    const float* be2 = (const float*)d_in[16];
    float* out = (float*)d_out;

    char* wsb = (char*)d_ws;
    size_t off = 0;
    auto alloc = [&](size_t bytes) {
        void* p = wsb + off;
        off += (bytes + 255) & ~(size_t)255;
        return p;
    };
    unsigned short* Qb   = (unsigned short*)alloc((size_t)NN * D * 2);
    unsigned short* Kb   = (unsigned short*)alloc((size_t)NN * D * 2);
    unsigned short* Vb   = (unsigned short*)alloc((size_t)NN * D * 2);
    float* hbuf          = (float*)alloc((size_t)NN * D * 4);
    float* hattn         = (float*)alloc((size_t)NN * D * 4);
    float* scb           = (float*)alloc((size_t)NE * 4 * 4);   // per-edge, per-head scores
    int* row_off         = (int*)alloc((size_t)(NN + 1) * 4);
    int* cursor          = (int*)alloc((size_t)NN * 4);
    int* deg             = (int*)alloc((size_t)NN * 4);
    int* csr_src         = (int*)alloc((size_t)NE * 4);
    int* eperm           = (int*)alloc((size_t)NE * 4);
    unsigned short* wqT  = (unsigned short*)alloc((size_t)2 * 4096 * 2);
    unsigned short* wkT  = (unsigned short*)alloc((size_t)2 * 4096 * 2);
    unsigned short* wvT  = (unsigned short*)alloc((size_t)2 * 4096 * 2);
    unsigned short* weT  = (unsigned short*)alloc((size_t)2 * 4096 * 2);
    unsigned short* woT  = (unsigned short*)alloc((size_t)2 * 4096 * 2);
    unsigned short* w1T  = (unsigned short*)alloc((size_t)2 * 8192 * 2);
    unsigned short* w2T  = (unsigned short*)alloc((size_t)2 * 8192 * 2);

    // CSR build + weight prep (once per call)
    hipMemsetAsync(deg, 0, (size_t)NN * 4, stream);
    k_deg<<<(NE + 255) / 256, 256, 0, stream>>>(ei, deg);
    k_scan<<<1, 1024, 0, stream>>>(deg, row_off, cursor);
    k_scatter<<<(NE + 255) / 256, 256, 0, stream>>>(ei, cursor, csr_src, eperm);
    k_prep<<<(2 * 36864 + 255) / 256, 256, 0, stream>>>(WQ, WK, WV, WE, WO, W1, W2,
            wqT, wkT, wvT, weT, woT, w1T, w2T);

    for (int l = 0; l < NL; l++) {
        const float* hcur = (l == 0) ? x : hbuf;
        float* hnxt = (l == NL - 1) ? out : hbuf;
        k_qkv_mfma<<<782, 256, 0, stream>>>(hcur, wqT + l * 4096, wkT + l * 4096,
                                            wvT + l * 4096, Qb, Kb, Vb);
        k_score<<<1024, 256, 0, stream>>>(ea, weT + l * 4096, ei, eperm, Qb, Kb, scb);
        k_agg<<<(NN + 3) / 4, 256, 0, stream>>>(Vb, scb, row_off, csr_src, hattn);
        k_post_mfma<<<(NN / 16 + 7) / 8, 512, 0, stream>>>(hcur, hattn,
                woT + l * 4096, w1T + l * 8192, w2T + l * 8192,
                bO + l * 64, g1 + l * 64, be1 + l * 64,
                b1 + l * 128, b2 + l * 64,
                g2 + l * 64, be2 + l * 64, hnxt);
    }
}